// Round 1
// baseline (1710.292 us; speedup 1.0000x reference)
//
#include <hip/hip_runtime.h>
#include <math.h>
#include <stdint.h>
#include <stddef.h>

#define NB 8
#define NC 256
#define NN 4096
#define NDQK 32
#define BN_EPS 1e-5f

static __device__ __forceinline__ float4 ld4(const float* p) { return *(const float4*)p; }
static __device__ __forceinline__ void st4(float* p, float4 v) { *(float4*)p = v; }

// ---------------------------------------------------------------------------
// Kernel 1: fused QKV 1x1-conv + BN(inference) + ReLU.
//   Per-batch GEMM: W[320,256] @ X[256,4096] ; rows 0..31=q, 32..63=k, 64..319=v
//   Output layouts (transposed for attention):
//     q_t,k_t : [B][N][32]   (query/key rows contiguous)
//     v_t     : [B][N][256]  (value rows contiguous)
//   WG tile: 64 o-rows x 128 n-cols, K-chunks of 64. 256 threads, 4o x 8n/thread.
// ---------------------------------------------------------------------------
__global__ __launch_bounds__(256) void qkv_fused(
    const float* __restrict__ x,
    const float* __restrict__ wq, const float* __restrict__ bq,
    const float* __restrict__ gq, const float* __restrict__ betaq,
    const float* __restrict__ mq, const float* __restrict__ vq,
    const float* __restrict__ wk, const float* __restrict__ bk,
    const float* __restrict__ gk, const float* __restrict__ betak,
    const float* __restrict__ mk, const float* __restrict__ vk,
    const float* __restrict__ wv, const float* __restrict__ bv,
    const float* __restrict__ gv, const float* __restrict__ betav,
    const float* __restrict__ mv, const float* __restrict__ vv,
    float* __restrict__ q_t, float* __restrict__ k_t, float* __restrict__ v_t)
{
  // smem: [0,8704) = sX [64][128] during compute, sT [128][68] in epilogue
  //       [8704, 13056) = sW [64][68]
  __shared__ __align__(16) float smem[13056];
  float* sX = smem;
  float* sW = smem + 8704;
  float* sT = smem;

  const int tid   = threadIdx.x;
  const int bx    = blockIdx.x;
  const int b     = bx & 7;          // batch on XCD bx%8
  const int rem   = bx >> 3;
  const int ntile = rem & 31;        // 0..31
  const int otile = rem >> 5;        // 0..4
  const int n0    = ntile * 128;
  const int o0    = otile * 64;

  const int to = tid >> 4;           // 0..15 -> o rows to*4..+3
  const int tn = tid & 15;           // 0..15 -> n cols tn*4 + r*64 + e

  float acc[4][2][4];
#pragma unroll
  for (int j = 0; j < 4; ++j)
#pragma unroll
    for (int r = 0; r < 2; ++r)
#pragma unroll
      for (int e = 0; e < 4; ++e) acc[j][r][e] = 0.f;

  const float* xb = x + (size_t)b * NC * NN + n0;

  for (int ch = 0; ch < 4; ++ch) {
    const int c0 = ch * 64;
    // stage X chunk [64 c][128 n]
#pragma unroll
    for (int p = 0; p < 8; ++p) {
      int f = p * 256 + tid;             // 2048 float4
      int row = f >> 5, col4 = f & 31;
      float4 t = ld4(xb + (size_t)(c0 + row) * NN + col4 * 4);
      st4(sX + row * 128 + col4 * 4, t);
    }
    // stage W chunk [64 o][64 c] (padded rows of 68)
#pragma unroll
    for (int p = 0; p < 4; ++p) {
      int f = p * 256 + tid;             // 1024 float4
      int row = f >> 4, col4 = f & 15;
      int o = o0 + row;
      const float* wrow;
      if (o < 32)      wrow = wq + o * NC;
      else if (o < 64) wrow = wk + (o - 32) * NC;
      else             wrow = wv + (o - 64) * NC;
      float4 t = ld4(wrow + c0 + col4 * 4);
      st4(sW + row * 68 + col4 * 4, t);
    }
    __syncthreads();

    for (int cc = 0; cc < 16; ++cc) {
      float wr[4][4];
#pragma unroll
      for (int j = 0; j < 4; ++j) {
        float4 t = ld4(sW + (to * 4 + j) * 68 + cc * 4);
        wr[j][0] = t.x; wr[j][1] = t.y; wr[j][2] = t.z; wr[j][3] = t.w;
      }
      float xr[4][2][4];
#pragma unroll
      for (int lc = 0; lc < 4; ++lc)
#pragma unroll
        for (int r = 0; r < 2; ++r) {
          float4 t = ld4(sX + (cc * 4 + lc) * 128 + tn * 4 + r * 64);
          xr[lc][r][0] = t.x; xr[lc][r][1] = t.y; xr[lc][r][2] = t.z; xr[lc][r][3] = t.w;
        }
#pragma unroll
      for (int j = 0; j < 4; ++j)
#pragma unroll
        for (int lc = 0; lc < 4; ++lc)
#pragma unroll
          for (int r = 0; r < 2; ++r)
#pragma unroll
            for (int e = 0; e < 4; ++e)
              acc[j][r][e] = fmaf(wr[j][lc], xr[lc][r][e], acc[j][r][e]);
    }
    __syncthreads();
  }

  // BN + ReLU, stage transposed [n][o] (pad 68) for coalesced stores
#pragma unroll
  for (int j = 0; j < 4; ++j) {
    int o = o0 + to * 4 + j;
    float bias, g, beta, mean, var;
    if (o < 32)      { int d = o;      bias = bq[d]; g = gq[d]; beta = betaq[d]; mean = mq[d]; var = vq[d]; }
    else if (o < 64) { int d = o - 32; bias = bk[d]; g = gk[d]; beta = betak[d]; mean = mk[d]; var = vk[d]; }
    else             { int d = o - 64; bias = bv[d]; g = gv[d]; beta = betav[d]; mean = mv[d]; var = vv[d]; }
    float alpha = g * rsqrtf(var + BN_EPS);
    float delta = (bias - mean) * alpha + beta;
#pragma unroll
    for (int r = 0; r < 2; ++r)
#pragma unroll
      for (int e = 0; e < 4; ++e) {
        float y = fmaf(acc[j][r][e], alpha, delta);
        y = fmaxf(y, 0.f);
        int n = tn * 4 + r * 64 + e;
        sT[n * 68 + to * 4 + j] = y;
      }
  }
  __syncthreads();

  const size_t nrow = (size_t)b * NN + n0;
#pragma unroll
  for (int p = 0; p < 8; ++p) {
    int f = p * 256 + tid;               // 2048 float4: [128 n][16 col4]
    int n = f >> 4, col4 = f & 15;
    float4 t = ld4(sT + n * 68 + col4 * 4);
    if (otile == 0) {
      if (col4 < 8) st4(q_t + (nrow + n) * 32 + col4 * 4, t);
      else          st4(k_t + (nrow + n) * 32 + (col4 - 8) * 4, t);
    } else {
      st4(v_t + (nrow + n) * 256 + (otile - 1) * 64 + col4 * 4, t);
    }
  }
}

// ---------------------------------------------------------------------------
// Kernel 2: flash attention (unscaled logits), fused epilogue gamma*out + x.
//   Per WG: batch b, 64 query rows. Loop 128 key-tiles of 32.
//   S mapping : thread = (si 0..63, jg 0..3), 8 j per thread (j = jg + jj*4)
//   PV mapping: thread = (pib = (t/16)*4 rows, cb = (t%16)*16 channels)
//   Q rows held in registers (32 VGPR). K,V,P staged in LDS.
// ---------------------------------------------------------------------------
__global__ __launch_bounds__(256) void attn_flash(
    const float* __restrict__ q_t, const float* __restrict__ k_t,
    const float* __restrict__ v_t, const float* __restrict__ x,
    const float* __restrict__ gamma, float* __restrict__ out)
{
  __shared__ __align__(16) float smem[11584];
  float* sV  = smem;            // [32][256]
  float* sK  = smem + 8192;     // [32][36]  (pad 36 -> j-broadcast groups on distinct banks)
  float* sP  = smem + 9344;     // [64][33]
  float* sSc = smem + 11456;    // [64] per-row rescale
  float* sL  = smem + 11520;    // [64] softmax denom

  const int tid   = threadIdx.x;
  const int b     = blockIdx.x & 7;
  const int itile = blockIdx.x >> 3;
  const int i0    = itile * 64;

  const int si  = tid >> 2, jg = tid & 3;
  const int pib = (tid >> 4) * 4, cb = (tid & 15) * 16;

  // Q row -> registers
  float qreg[32];
  {
    const float* qrow = q_t + ((size_t)b * NN + i0 + si) * 32;
#pragma unroll
    for (int d4 = 0; d4 < 8; ++d4) {
      float4 t = ld4(qrow + d4 * 4);
      qreg[d4 * 4 + 0] = t.x; qreg[d4 * 4 + 1] = t.y;
      qreg[d4 * 4 + 2] = t.z; qreg[d4 * 4 + 3] = t.w;
    }
  }

  float m = -INFINITY, l = 0.f;
  float acc[4][16];
#pragma unroll
  for (int ii = 0; ii < 4; ++ii)
#pragma unroll
    for (int q = 0; q < 16; ++q) acc[ii][q] = 0.f;

  const float* kb = k_t + (size_t)b * NN * 32;
  const float* vb = v_t + (size_t)b * NN * 256;

  for (int jt = 0; jt < 128; ++jt) {
    const int j0 = jt * 32;
    // stage K tile (contiguous 4 KB)
    {
      float4 t = ld4(kb + (size_t)j0 * 32 + tid * 4);
      int j = tid >> 3, d4 = tid & 7;
      st4(sK + j * 36 + d4 * 4, t);
    }
    // stage V tile (contiguous 32 KB)
    {
      const float* vt0 = vb + (size_t)j0 * 256;
#pragma unroll
      for (int p = 0; p < 8; ++p) {
        int f = p * 256 + tid;
        st4(sV + f * 4, ld4(vt0 + f * 4));
      }
    }
    __syncthreads();

    // ---- S = Q K^T  (8 logits per thread) + online softmax ----
    float pv[8];
    float tmax = -INFINITY;
#pragma unroll
    for (int jj = 0; jj < 8; ++jj) {
      int j = jg + jj * 4;
      float s = 0.f;
#pragma unroll
      for (int d4 = 0; d4 < 8; ++d4) {
        float4 kf = ld4(sK + j * 36 + d4 * 4);
        s = fmaf(qreg[d4 * 4 + 0], kf.x, s);
        s = fmaf(qreg[d4 * 4 + 1], kf.y, s);
        s = fmaf(qreg[d4 * 4 + 2], kf.z, s);
        s = fmaf(qreg[d4 * 4 + 3], kf.w, s);
      }
      pv[jj] = s;
      tmax = fmaxf(tmax, s);
    }
    tmax = fmaxf(tmax, __shfl_xor(tmax, 1));
    tmax = fmaxf(tmax, __shfl_xor(tmax, 2));
    float mnew  = fmaxf(m, tmax);
    float scale = __expf(m - mnew);     // first tile: exp(-inf)=0
    float tsum  = 0.f;
#pragma unroll
    for (int jj = 0; jj < 8; ++jj) {
      float p = __expf(pv[jj] - mnew);
      pv[jj] = p;
      tsum += p;
    }
    tsum += __shfl_xor(tsum, 1);
    tsum += __shfl_xor(tsum, 2);
    l = fmaf(l, scale, tsum);
    m = mnew;
#pragma unroll
    for (int jj = 0; jj < 8; ++jj) sP[si * 33 + jg + jj * 4] = pv[jj];
    if (jg == 0) sSc[si] = scale;
    __syncthreads();

    // ---- O = O*scale + P V  (4 rows x 16 channels per thread) ----
    float rs[4];
#pragma unroll
    for (int ii = 0; ii < 4; ++ii) rs[ii] = sSc[pib + ii];
#pragma unroll
    for (int ii = 0; ii < 4; ++ii)
#pragma unroll
      for (int q = 0; q < 16; ++q) acc[ii][q] *= rs[ii];

#pragma unroll 4
    for (int j = 0; j < 32; ++j) {
      float4 vf[4];
#pragma unroll
      for (int q = 0; q < 4; ++q) vf[q] = ld4(sV + j * 256 + cb + q * 4);
#pragma unroll
      for (int ii = 0; ii < 4; ++ii) {
        float p = sP[(pib + ii) * 33 + j];
        acc[ii][0]  = fmaf(p, vf[0].x, acc[ii][0]);
        acc[ii][1]  = fmaf(p, vf[0].y, acc[ii][1]);
        acc[ii][2]  = fmaf(p, vf[0].z, acc[ii][2]);
        acc[ii][3]  = fmaf(p, vf[0].w, acc[ii][3]);
        acc[ii][4]  = fmaf(p, vf[1].x, acc[ii][4]);
        acc[ii][5]  = fmaf(p, vf[1].y, acc[ii][5]);
        acc[ii][6]  = fmaf(p, vf[1].z, acc[ii][6]);
        acc[ii][7]  = fmaf(p, vf[1].w, acc[ii][7]);
        acc[ii][8]  = fmaf(p, vf[2].x, acc[ii][8]);
        acc[ii][9]  = fmaf(p, vf[2].y, acc[ii][9]);
        acc[ii][10] = fmaf(p, vf[2].z, acc[ii][10]);
        acc[ii][11] = fmaf(p, vf[2].w, acc[ii][11]);
        acc[ii][12] = fmaf(p, vf[3].x, acc[ii][12]);
        acc[ii][13] = fmaf(p, vf[3].y, acc[ii][13]);
        acc[ii][14] = fmaf(p, vf[3].z, acc[ii][14]);
        acc[ii][15] = fmaf(p, vf[3].w, acc[ii][15]);
      }
    }
    __syncthreads();
  }

  // ---- epilogue: out = gamma * (acc / l) + x, coalesced via LDS transpose ----
  if (jg == 0) sL[si] = l;
  __syncthreads();
  float linv[4];
#pragma unroll
  for (int ii = 0; ii < 4; ++ii) linv[ii] = 1.f / sL[pib + ii];
  const float gm = gamma[0];
  float* sT = smem;                     // reuse as [128 c][64 i]
  const float* xb = x + (size_t)b * NC * NN + i0;
  float* ob = out + (size_t)b * NC * NN + i0;

  for (int half = 0; half < 2; ++half) {
    if ((cb >> 7) == half) {
      int cl0 = cb & 127;
#pragma unroll
      for (int ii = 0; ii < 4; ++ii)
#pragma unroll
        for (int q = 0; q < 16; ++q)
          sT[(cl0 + q) * 64 + pib + ii] = acc[ii][q] * linv[ii];
    }
    __syncthreads();
#pragma unroll
    for (int p = 0; p < 8; ++p) {
      int f = p * 256 + tid;            // 2048 float4: [128 c][16 col4]
      int cl = f >> 4, col4 = f & 15;
      size_t off = (size_t)(half * 128 + cl) * NN + col4 * 4;
      float4 xv = ld4(xb + off);
      float4 tv = ld4(sT + cl * 64 + col4 * 4);
      float4 o4;
      o4.x = fmaf(gm, tv.x, xv.x);
      o4.y = fmaf(gm, tv.y, xv.y);
      o4.z = fmaf(gm, tv.z, xv.z);
      o4.w = fmaf(gm, tv.w, xv.w);
      st4(ob + off, o4);
    }
    __syncthreads();
  }
}

// ---------------------------------------------------------------------------
extern "C" void kernel_launch(void* const* d_in, const int* in_sizes, int n_in,
                              void* d_out, int out_size, void* d_ws, size_t ws_size,
                              hipStream_t stream) {
  const float* x     = (const float*)d_in[0];
  const float* wq    = (const float*)d_in[1];
  const float* bq    = (const float*)d_in[2];
  const float* gq    = (const float*)d_in[3];
  const float* betaq = (const float*)d_in[4];
  const float* mq    = (const float*)d_in[5];
  const float* vq    = (const float*)d_in[6];
  const float* wk    = (const float*)d_in[7];
  const float* bk    = (const float*)d_in[8];
  const float* gk    = (const float*)d_in[9];
  const float* betak = (const float*)d_in[10];
  const float* mk    = (const float*)d_in[11];
  const float* vk    = (const float*)d_in[12];
  const float* wv    = (const float*)d_in[13];
  const float* bv    = (const float*)d_in[14];
  const float* gv    = (const float*)d_in[15];
  const float* betav = (const float*)d_in[16];
  const float* mv    = (const float*)d_in[17];
  const float* vv    = (const float*)d_in[18];
  const float* gamma = (const float*)d_in[19];
  float* out = (float*)d_out;

  // workspace: q_t 4MB | k_t 4MB | v_t 32MB  (requires ~42MB of d_ws)
  float* q_t = (float*)d_ws;
  float* k_t = q_t + (size_t)NB * NN * NDQK;
  float* v_t = k_t + (size_t)NB * NN * NDQK;

  qkv_fused<<<dim3(1280), dim3(256), 0, stream>>>(
      x, wq, bq, gq, betaq, mq, vq,
      wk, bk, gk, betak, mk, vk,
      wv, bv, gv, betav, mv, vv,
      q_t, k_t, v_t);

  attn_flash<<<dim3(512), dim3(256), 0, stream>>>(q_t, k_t, v_t, x, gamma, out);
}

// Round 2
// 1306.907 us; speedup vs baseline: 1.3087x; 1.3087x over previous
//
#include <hip/hip_runtime.h>
#include <math.h>
#include <stdint.h>
#include <stddef.h>

#define NB 8
#define NC 256
#define NN 4096
#define NDQK 32
#define BN_EPS 1e-5f

static __device__ __forceinline__ float4 ld4(const float* p) { return *(const float4*)p; }
static __device__ __forceinline__ void st4(float* p, float4 v) { *(float4*)p = v; }

// ---------------------------------------------------------------------------
// Kernel 1: fused QKV 1x1-conv + BN(inference) + ReLU.  (unchanged from R1)
// ---------------------------------------------------------------------------
__global__ __launch_bounds__(256) void qkv_fused(
    const float* __restrict__ x,
    const float* __restrict__ wq, const float* __restrict__ bq,
    const float* __restrict__ gq, const float* __restrict__ betaq,
    const float* __restrict__ mq, const float* __restrict__ vq,
    const float* __restrict__ wk, const float* __restrict__ bk,
    const float* __restrict__ gk, const float* __restrict__ betak,
    const float* __restrict__ mk, const float* __restrict__ vk,
    const float* __restrict__ wv, const float* __restrict__ bv,
    const float* __restrict__ gv, const float* __restrict__ betav,
    const float* __restrict__ mv, const float* __restrict__ vv,
    float* __restrict__ q_t, float* __restrict__ k_t, float* __restrict__ v_t)
{
  __shared__ __align__(16) float smem[13056];
  float* sX = smem;
  float* sW = smem + 8704;
  float* sT = smem;

  const int tid   = threadIdx.x;
  const int bx    = blockIdx.x;
  const int b     = bx & 7;
  const int rem   = bx >> 3;
  const int ntile = rem & 31;
  const int otile = rem >> 5;
  const int n0    = ntile * 128;
  const int o0    = otile * 64;

  const int to = tid >> 4;
  const int tn = tid & 15;

  float acc[4][2][4];
#pragma unroll
  for (int j = 0; j < 4; ++j)
#pragma unroll
    for (int r = 0; r < 2; ++r)
#pragma unroll
      for (int e = 0; e < 4; ++e) acc[j][r][e] = 0.f;

  const float* xb = x + (size_t)b * NC * NN + n0;

  for (int ch = 0; ch < 4; ++ch) {
    const int c0 = ch * 64;
#pragma unroll
    for (int p = 0; p < 8; ++p) {
      int f = p * 256 + tid;
      int row = f >> 5, col4 = f & 31;
      float4 t = ld4(xb + (size_t)(c0 + row) * NN + col4 * 4);
      st4(sX + row * 128 + col4 * 4, t);
    }
#pragma unroll
    for (int p = 0; p < 4; ++p) {
      int f = p * 256 + tid;
      int row = f >> 4, col4 = f & 15;
      int o = o0 + row;
      const float* wrow;
      if (o < 32)      wrow = wq + o * NC;
      else if (o < 64) wrow = wk + (o - 32) * NC;
      else             wrow = wv + (o - 64) * NC;
      float4 t = ld4(wrow + c0 + col4 * 4);
      st4(sW + row * 68 + col4 * 4, t);
    }
    __syncthreads();

    for (int cc = 0; cc < 16; ++cc) {
      float wr[4][4];
#pragma unroll
      for (int j = 0; j < 4; ++j) {
        float4 t = ld4(sW + (to * 4 + j) * 68 + cc * 4);
        wr[j][0] = t.x; wr[j][1] = t.y; wr[j][2] = t.z; wr[j][3] = t.w;
      }
      float xr[4][2][4];
#pragma unroll
      for (int lc = 0; lc < 4; ++lc)
#pragma unroll
        for (int r = 0; r < 2; ++r) {
          float4 t = ld4(sX + (cc * 4 + lc) * 128 + tn * 4 + r * 64);
          xr[lc][r][0] = t.x; xr[lc][r][1] = t.y; xr[lc][r][2] = t.z; xr[lc][r][3] = t.w;
        }
#pragma unroll
      for (int j = 0; j < 4; ++j)
#pragma unroll
        for (int lc = 0; lc < 4; ++lc)
#pragma unroll
          for (int r = 0; r < 2; ++r)
#pragma unroll
            for (int e = 0; e < 4; ++e)
              acc[j][r][e] = fmaf(wr[j][lc], xr[lc][r][e], acc[j][r][e]);
    }
    __syncthreads();
  }

#pragma unroll
  for (int j = 0; j < 4; ++j) {
    int o = o0 + to * 4 + j;
    float bias, g, beta, mean, var;
    if (o < 32)      { int d = o;      bias = bq[d]; g = gq[d]; beta = betaq[d]; mean = mq[d]; var = vq[d]; }
    else if (o < 64) { int d = o - 32; bias = bk[d]; g = gk[d]; beta = betak[d]; mean = mk[d]; var = vk[d]; }
    else             { int d = o - 64; bias = bv[d]; g = gv[d]; beta = betav[d]; mean = mv[d]; var = vv[d]; }
    float alpha = g * rsqrtf(var + BN_EPS);
    float delta = (bias - mean) * alpha + beta;
#pragma unroll
    for (int r = 0; r < 2; ++r)
#pragma unroll
      for (int e = 0; e < 4; ++e) {
        float y = fmaf(acc[j][r][e], alpha, delta);
        y = fmaxf(y, 0.f);
        int n = tn * 4 + r * 64 + e;
        sT[n * 68 + to * 4 + j] = y;
      }
  }
  __syncthreads();

  const size_t nrow = (size_t)b * NN + n0;
#pragma unroll
  for (int p = 0; p < 8; ++p) {
    int f = p * 256 + tid;
    int n = f >> 4, col4 = f & 15;
    float4 t = ld4(sT + n * 68 + col4 * 4);
    if (otile == 0) {
      if (col4 < 8) st4(q_t + (nrow + n) * 32 + col4 * 4, t);
      else          st4(k_t + (nrow + n) * 32 + (col4 - 8) * 4, t);
    } else {
      st4(v_t + (nrow + n) * 256 + (otile - 1) * 64 + col4 * 4, t);
    }
  }
}

// ---------------------------------------------------------------------------
// Kernel 2: flash attention (unscaled logits), fused epilogue gamma*out + x.
//   R2 change: bank-conflict-free PV mapping.
//   PV thread tile: rows pib..pib+3 (pib=(tid>>4)*4), channels c = tl*4+q*64+e
//   (tl = tid&15, q=0..3, e=0..3). V read sV + j*256 + tl*4 + q*64:
//   lanes 0..15 cover all 32 banks 2x (free), lanes 16..63 broadcast.
//   sP padded to stride 36 (bank = si*4+jg -> 2-way max).
// ---------------------------------------------------------------------------
__global__ __launch_bounds__(256) void attn_flash(
    const float* __restrict__ q_t, const float* __restrict__ k_t,
    const float* __restrict__ v_t, const float* __restrict__ x,
    const float* __restrict__ gamma, float* __restrict__ out)
{
  __shared__ __align__(16) float smem[11776];
  float* sV  = smem;            // [32][256]
  float* sK  = smem + 8192;     // [32][36]
  float* sP  = smem + 9344;     // [64][36]
  float* sSc = smem + 11648;    // [64]
  float* sL  = smem + 11712;    // [64]

  const int tid   = threadIdx.x;
  const int b     = blockIdx.x & 7;
  const int itile = blockIdx.x >> 3;
  const int i0    = itile * 64;

  const int si  = tid >> 2, jg = tid & 3;
  const int pib = (tid >> 4) * 4;
  const int tl  = tid & 15;

  float qreg[32];
  {
    const float* qrow = q_t + ((size_t)b * NN + i0 + si) * 32;
#pragma unroll
    for (int d4 = 0; d4 < 8; ++d4) {
      float4 t = ld4(qrow + d4 * 4);
      qreg[d4 * 4 + 0] = t.x; qreg[d4 * 4 + 1] = t.y;
      qreg[d4 * 4 + 2] = t.z; qreg[d4 * 4 + 3] = t.w;
    }
  }

  float m = -INFINITY, l = 0.f;
  float acc[4][16];   // [ii][q*4+e] -> row pib+ii, channel tl*4 + q*64 + e
#pragma unroll
  for (int ii = 0; ii < 4; ++ii)
#pragma unroll
    for (int q = 0; q < 16; ++q) acc[ii][q] = 0.f;

  const float* kb = k_t + (size_t)b * NN * 32;
  const float* vb = v_t + (size_t)b * NN * 256;

  for (int jt = 0; jt < 128; ++jt) {
    const int j0 = jt * 32;
    {
      float4 t = ld4(kb + (size_t)j0 * 32 + tid * 4);
      int j = tid >> 3, d4 = tid & 7;
      st4(sK + j * 36 + d4 * 4, t);
    }
    {
      const float* vt0 = vb + (size_t)j0 * 256;
#pragma unroll
      for (int p = 0; p < 8; ++p) {
        int f = p * 256 + tid;
        st4(sV + f * 4, ld4(vt0 + f * 4));
      }
    }
    __syncthreads();

    // ---- S = Q K^T (8 logits/thread) + online softmax ----
    float pv[8];
    float tmax = -INFINITY;
#pragma unroll
    for (int jj = 0; jj < 8; ++jj) {
      int j = jg + jj * 4;
      float s = 0.f;
#pragma unroll
      for (int d4 = 0; d4 < 8; ++d4) {
        float4 kf = ld4(sK + j * 36 + d4 * 4);
        s = fmaf(qreg[d4 * 4 + 0], kf.x, s);
        s = fmaf(qreg[d4 * 4 + 1], kf.y, s);
        s = fmaf(qreg[d4 * 4 + 2], kf.z, s);
        s = fmaf(qreg[d4 * 4 + 3], kf.w, s);
      }
      pv[jj] = s;
      tmax = fmaxf(tmax, s);
    }
    tmax = fmaxf(tmax, __shfl_xor(tmax, 1));
    tmax = fmaxf(tmax, __shfl_xor(tmax, 2));
    float mnew  = fmaxf(m, tmax);
    float scale = __expf(m - mnew);
    float tsum  = 0.f;
#pragma unroll
    for (int jj = 0; jj < 8; ++jj) {
      float p = __expf(pv[jj] - mnew);
      pv[jj] = p;
      tsum += p;
    }
    tsum += __shfl_xor(tsum, 1);
    tsum += __shfl_xor(tsum, 2);
    l = fmaf(l, scale, tsum);
    m = mnew;
#pragma unroll
    for (int jj = 0; jj < 8; ++jj) sP[si * 36 + jg + jj * 4] = pv[jj];
    if (jg == 0) sSc[si] = scale;
    __syncthreads();

    // ---- O = O*scale + P V (4 rows x 4 strided float4s per thread) ----
    float rs[4];
#pragma unroll
    for (int ii = 0; ii < 4; ++ii) rs[ii] = sSc[pib + ii];
#pragma unroll
    for (int ii = 0; ii < 4; ++ii)
#pragma unroll
      for (int q = 0; q < 16; ++q) acc[ii][q] *= rs[ii];

#pragma unroll 4
    for (int j = 0; j < 32; ++j) {
      float4 vf[4];
#pragma unroll
      for (int q = 0; q < 4; ++q) vf[q] = ld4(sV + j * 256 + tl * 4 + q * 64);
#pragma unroll
      for (int ii = 0; ii < 4; ++ii) {
        float p = sP[(pib + ii) * 36 + j];
        acc[ii][0]  = fmaf(p, vf[0].x, acc[ii][0]);
        acc[ii][1]  = fmaf(p, vf[0].y, acc[ii][1]);
        acc[ii][2]  = fmaf(p, vf[0].z, acc[ii][2]);
        acc[ii][3]  = fmaf(p, vf[0].w, acc[ii][3]);
        acc[ii][4]  = fmaf(p, vf[1].x, acc[ii][4]);
        acc[ii][5]  = fmaf(p, vf[1].y, acc[ii][5]);
        acc[ii][6]  = fmaf(p, vf[1].z, acc[ii][6]);
        acc[ii][7]  = fmaf(p, vf[1].w, acc[ii][7]);
        acc[ii][8]  = fmaf(p, vf[2].x, acc[ii][8]);
        acc[ii][9]  = fmaf(p, vf[2].y, acc[ii][9]);
        acc[ii][10] = fmaf(p, vf[2].z, acc[ii][10]);
        acc[ii][11] = fmaf(p, vf[2].w, acc[ii][11]);
        acc[ii][12] = fmaf(p, vf[3].x, acc[ii][12]);
        acc[ii][13] = fmaf(p, vf[3].y, acc[ii][13]);
        acc[ii][14] = fmaf(p, vf[3].z, acc[ii][14]);
        acc[ii][15] = fmaf(p, vf[3].w, acc[ii][15]);
      }
    }
    __syncthreads();
  }

  // ---- epilogue: out = gamma * (acc / l) + x ----
  if (jg == 0) sL[si] = l;
  __syncthreads();
  float linv[4];
#pragma unroll
  for (int ii = 0; ii < 4; ++ii) linv[ii] = 1.f / sL[pib + ii];
  const float gm = gamma[0];
  float* sT = smem;                     // reuse as [128 c][68]
  const float* xb = x + (size_t)b * NC * NN + i0;
  float* ob = out + (size_t)b * NC * NN + i0;

  for (int half = 0; half < 2; ++half) {
#pragma unroll
    for (int qq = 0; qq < 2; ++qq) {
      int q = half * 2 + qq;            // global q
#pragma unroll
      for (int e = 0; e < 4; ++e) {
        int cl = qq * 64 + tl * 4 + e;  // channel within half
#pragma unroll
        for (int ii = 0; ii < 4; ++ii)
          sT[cl * 68 + pib + ii] = acc[ii][q * 4 + e] * linv[ii];
      }
    }
    __syncthreads();
#pragma unroll
    for (int p = 0; p < 8; ++p) {
      int f = p * 256 + tid;            // 2048 float4: [128 c][16 col4]
      int cl = f >> 4, col4 = f & 15;
      size_t off = (size_t)(half * 128 + cl) * NN + col4 * 4;
      float4 xv = ld4(xb + off);
      float4 tv = ld4(sT + cl * 68 + col4 * 4);
      float4 o4;
      o4.x = fmaf(gm, tv.x, xv.x);
      o4.y = fmaf(gm, tv.y, xv.y);
      o4.z = fmaf(gm, tv.z, xv.z);
      o4.w = fmaf(gm, tv.w, xv.w);
      st4(ob + off, o4);
    }
    __syncthreads();
  }
}

// ---------------------------------------------------------------------------
extern "C" void kernel_launch(void* const* d_in, const int* in_sizes, int n_in,
                              void* d_out, int out_size, void* d_ws, size_t ws_size,
                              hipStream_t stream) {
  const float* x     = (const float*)d_in[0];
  const float* wq    = (const float*)d_in[1];
  const float* bq    = (const float*)d_in[2];
  const float* gq    = (const float*)d_in[3];
  const float* betaq = (const float*)d_in[4];
  const float* mq    = (const float*)d_in[5];
  const float* vq    = (const float*)d_in[6];
  const float* wk    = (const float*)d_in[7];
  const float* bk    = (const float*)d_in[8];
  const float* gk    = (const float*)d_in[9];
  const float* betak = (const float*)d_in[10];
  const float* mk    = (const float*)d_in[11];
  const float* vk    = (const float*)d_in[12];
  const float* wv    = (const float*)d_in[13];
  const float* bv    = (const float*)d_in[14];
  const float* gv    = (const float*)d_in[15];
  const float* betav = (const float*)d_in[16];
  const float* mv    = (const float*)d_in[17];
  const float* vv    = (const float*)d_in[18];
  const float* gamma = (const float*)d_in[19];
  float* out = (float*)d_out;

  float* q_t = (float*)d_ws;
  float* k_t = q_t + (size_t)NB * NN * NDQK;
  float* v_t = k_t + (size_t)NB * NN * NDQK;

  qkv_fused<<<dim3(1280), dim3(256), 0, stream>>>(
      x, wq, bq, gq, betaq, mq, vq,
      wk, bk, gk, betak, mk, vk,
      wv, bv, gv, betav, mv, vv,
      q_t, k_t, v_t);

  attn_flash<<<dim3(512), dim3(256), 0, stream>>>(q_t, k_t, v_t, x, gamma, out);
}

// Round 3
// 610.676 us; speedup vs baseline: 2.8007x; 2.1401x over previous
//
#include <hip/hip_runtime.h>
#include <math.h>
#include <stdint.h>
#include <stddef.h>

#define NB 8
#define NC 256
#define NN 4096
#define BN_EPS 1e-5f

typedef unsigned short u16;
typedef __attribute__((ext_vector_type(4))) unsigned short u16x4;
typedef __attribute__((ext_vector_type(8))) short bf16x8;   // 8 bf16 = 4 VGPR
typedef __attribute__((ext_vector_type(4))) float f32x4;

static __device__ __forceinline__ float4 ld4(const float* p) { return *(const float4*)p; }
static __device__ __forceinline__ void st4(float* p, float4 v) { *(float4*)p = v; }
static __device__ __forceinline__ u16 f2bf(float f) {
  uint32_t u = __float_as_uint(f);
  return (u16)((u + 0x7FFFu + ((u >> 16) & 1u)) >> 16);   // RNE
}

// ---------------------------------------------------------------------------
// Kernel 1: fused QKV 1x1-conv + BN + ReLU. fp32 GEMM, bf16 outputs.
//   q_bf,k_bf : [B][N][32] bf16 (row n contiguous)
//   v_bf      : [B][C][N] bf16 (natural GEMM orientation, no transpose)
// ---------------------------------------------------------------------------
__global__ __launch_bounds__(256) void qkv_fused(
    const float* __restrict__ x,
    const float* __restrict__ wq, const float* __restrict__ bq,
    const float* __restrict__ gq, const float* __restrict__ betaq,
    const float* __restrict__ mq, const float* __restrict__ vq,
    const float* __restrict__ wk, const float* __restrict__ bk,
    const float* __restrict__ gk, const float* __restrict__ betak,
    const float* __restrict__ mk, const float* __restrict__ vk,
    const float* __restrict__ wv, const float* __restrict__ bv,
    const float* __restrict__ gv, const float* __restrict__ betav,
    const float* __restrict__ mv, const float* __restrict__ vv,
    u16* __restrict__ q_bf, u16* __restrict__ k_bf, u16* __restrict__ v_bf)
{
  __shared__ __align__(16) float smem[13056];
  float* sX = smem;
  float* sW = smem + 8704;
  float* sT = smem;

  const int tid   = threadIdx.x;
  const int bx    = blockIdx.x;
  const int b     = bx & 7;
  const int rem   = bx >> 3;
  const int ntile = rem & 31;
  const int otile = rem >> 5;
  const int n0    = ntile * 128;
  const int o0    = otile * 64;

  const int to = tid >> 4;
  const int tn = tid & 15;

  float acc[4][2][4];
#pragma unroll
  for (int j = 0; j < 4; ++j)
#pragma unroll
    for (int r = 0; r < 2; ++r)
#pragma unroll
      for (int e = 0; e < 4; ++e) acc[j][r][e] = 0.f;

  const float* xb = x + (size_t)b * NC * NN + n0;

  for (int ch = 0; ch < 4; ++ch) {
    const int c0 = ch * 64;
#pragma unroll
    for (int p = 0; p < 8; ++p) {
      int f = p * 256 + tid;
      int row = f >> 5, col4 = f & 31;
      float4 t = ld4(xb + (size_t)(c0 + row) * NN + col4 * 4);
      st4(sX + row * 128 + col4 * 4, t);
    }
#pragma unroll
    for (int p = 0; p < 4; ++p) {
      int f = p * 256 + tid;
      int row = f >> 4, col4 = f & 15;
      int o = o0 + row;
      const float* wrow;
      if (o < 32)      wrow = wq + o * NC;
      else if (o < 64) wrow = wk + (o - 32) * NC;
      else             wrow = wv + (o - 64) * NC;
      float4 t = ld4(wrow + c0 + col4 * 4);
      st4(sW + row * 68 + col4 * 4, t);
    }
    __syncthreads();

    for (int cc = 0; cc < 16; ++cc) {
      float wr[4][4];
#pragma unroll
      for (int j = 0; j < 4; ++j) {
        float4 t = ld4(sW + (to * 4 + j) * 68 + cc * 4);
        wr[j][0] = t.x; wr[j][1] = t.y; wr[j][2] = t.z; wr[j][3] = t.w;
      }
      float xr[4][2][4];
#pragma unroll
      for (int lc = 0; lc < 4; ++lc)
#pragma unroll
        for (int r = 0; r < 2; ++r) {
          float4 t = ld4(sX + (cc * 4 + lc) * 128 + tn * 4 + r * 64);
          xr[lc][r][0] = t.x; xr[lc][r][1] = t.y; xr[lc][r][2] = t.z; xr[lc][r][3] = t.w;
        }
#pragma unroll
      for (int j = 0; j < 4; ++j)
#pragma unroll
        for (int lc = 0; lc < 4; ++lc)
#pragma unroll
          for (int r = 0; r < 2; ++r)
#pragma unroll
            for (int e = 0; e < 4; ++e)
              acc[j][r][e] = fmaf(wr[j][lc], xr[lc][r][e], acc[j][r][e]);
    }
    __syncthreads();
  }

  if (otile == 0) {
    // q/k: BN+ReLU -> sT [n][64 o] -> bf16 stores
#pragma unroll
    for (int j = 0; j < 4; ++j) {
      int o = to * 4 + j;
      float bias, g, beta, mean, var;
      if (o < 32) { int d = o;      bias = bq[d]; g = gq[d]; beta = betaq[d]; mean = mq[d]; var = vq[d]; }
      else        { int d = o - 32; bias = bk[d]; g = gk[d]; beta = betak[d]; mean = mk[d]; var = vk[d]; }
      float alpha = g * rsqrtf(var + BN_EPS);
      float delta = (bias - mean) * alpha + beta;
#pragma unroll
      for (int r = 0; r < 2; ++r)
#pragma unroll
        for (int e = 0; e < 4; ++e) {
          float y = fmaxf(fmaf(acc[j][r][e], alpha, delta), 0.f);
          int n = tn * 4 + r * 64 + e;
          sT[n * 68 + to * 4 + j] = y;
        }
    }
    __syncthreads();
    const size_t nrow = (size_t)b * NN + n0;
#pragma unroll
    for (int p = 0; p < 8; ++p) {
      int f = p * 256 + tid;
      int n = f >> 4, col4 = f & 15;
      float4 t = ld4(sT + n * 68 + col4 * 4);
      u16x4 h = { f2bf(t.x), f2bf(t.y), f2bf(t.z), f2bf(t.w) };
      if (col4 < 8) *(u16x4*)(q_bf + (nrow + n) * 32 + col4 * 4) = h;
      else          *(u16x4*)(k_bf + (nrow + n) * 32 + (col4 - 8) * 4) = h;
    }
  } else {
    // v: BN+ReLU, direct bf16 store in [c][n] orientation (coalesced along n)
#pragma unroll
    for (int j = 0; j < 4; ++j) {
      int c = (otile - 1) * 64 + to * 4 + j;
      float alpha = gv[c] * rsqrtf(vv[c] + BN_EPS);
      float delta = (bv[c] - mv[c]) * alpha + betav[c];
#pragma unroll
      for (int r = 0; r < 2; ++r) {
        u16x4 h;
#pragma unroll
        for (int e = 0; e < 4; ++e)
          h[e] = f2bf(fmaxf(fmaf(acc[j][r][e], alpha, delta), 0.f));
        int n = n0 + tn * 4 + r * 64;
        *(u16x4*)(v_bf + ((size_t)b * NC + c) * NN + n) = h;
      }
    }
  }
}

// ---------------------------------------------------------------------------
// Kernel 2: MFMA flash attention. 1 wave per WG, 32 query rows, j-tiles of 64.
//   S = Q K^T via mfma_f32_16x16x32_bf16 (K=32=DQK, one MFMA per S tile).
//   K,V B-frags read directly from global (per-batch K+V lives in XCD L2;
//   b = blockIdx&7 pins batch b's WGs to XCD b).
//   P transposed through 4KB XOR-swizzled LDS (u16 writes, b128 frag reads).
//   Online softmax per 16-lane group; defer-rescale gate (T13-style).
// ---------------------------------------------------------------------------
__global__ __launch_bounds__(64, 2) void attn_mfma(
    const u16* __restrict__ q_bf, const u16* __restrict__ k_bf,
    const u16* __restrict__ v_bf, const float* __restrict__ x,
    const float* __restrict__ gamma, float* __restrict__ out)
{
  __shared__ u16 sP[32 * 64];                 // swizzled P tile (32 i x 64 j)
  __shared__ __align__(16) float sE[256 * 36]; // epilogue transpose

  const int l  = threadIdx.x;
  const int xl = l & 15;
  const int g  = l >> 4;
  const int b  = blockIdx.x & 7;
  const int rt = blockIdx.x >> 3;             // 0..127
  const int i0 = rt * 32;

  const u16* qb = q_bf + ((size_t)b * NN + i0) * 32;
  const u16* kb = k_bf + (size_t)b * NN * 32;
  const u16* vb = v_bf + (size_t)b * NC * NN;

  // Q A-frags (held all kernel): lane holds Q[i=xl][k=8g..8g+7]
  bf16x8 qf[2];
#pragma unroll
  for (int blk = 0; blk < 2; ++blk)
    qf[blk] = *(const bf16x8*)(qb + (size_t)(blk * 16 + xl) * 32 + 8 * g);

  f32x4 acc[2][16];
#pragma unroll
  for (int blk = 0; blk < 2; ++blk)
#pragma unroll
    for (int ct = 0; ct < 16; ++ct)
      acc[blk][ct] = (f32x4){0.f, 0.f, 0.f, 0.f};

  float mr[2][4], lr[2][4];
#pragma unroll
  for (int blk = 0; blk < 2; ++blk)
#pragma unroll
    for (int r = 0; r < 4; ++r) { mr[blk][r] = -INFINITY; lr[blk][r] = 0.f; }

  for (int jt64 = 0; jt64 < 64; ++jt64) {
    const int j0 = jt64 * 64;

    // K B-frags: lane holds K^T[k=8g..8g+7][j=xl] = k_bf[row 16jb+xl][8g..]
    bf16x8 kf[4];
#pragma unroll
    for (int jb = 0; jb < 4; ++jb)
      kf[jb] = *(const bf16x8*)(kb + (size_t)(j0 + 16 * jb + xl) * 32 + 8 * g);

#pragma unroll
    for (int blk = 0; blk < 2; ++blk) {
      f32x4 s[4];
#pragma unroll
      for (int jb = 0; jb < 4; ++jb)
        s[jb] = __builtin_amdgcn_mfma_f32_16x16x32_bf16(
            qf[blk], kf[jb], (f32x4){0.f, 0.f, 0.f, 0.f}, 0, 0, 0);
      // lane now holds S[rows 4g+r][col xl] per jb-tile of 16 cols
      float pm[4];
#pragma unroll
      for (int r = 0; r < 4; ++r)
        pm[r] = fmaxf(fmaxf(s[0][r], s[1][r]), fmaxf(s[2][r], s[3][r]));
#pragma unroll
      for (int msk = 1; msk < 16; msk <<= 1)
#pragma unroll
        for (int r = 0; r < 4; ++r)
          pm[r] = fmaxf(pm[r], __shfl_xor(pm[r], msk));

      bool need = false;
#pragma unroll
      for (int r = 0; r < 4; ++r) need = need || (pm[r] > mr[blk][r]);
      if (__any(need)) {
        float sc[4];
#pragma unroll
        for (int r = 0; r < 4; ++r) {
          float mn = fmaxf(mr[blk][r], pm[r]);
          sc[r] = __expf(mr[blk][r] - mn);
          mr[blk][r] = mn;
          lr[blk][r] *= sc[r];
        }
#pragma unroll
        for (int ct = 0; ct < 16; ++ct)
#pragma unroll
          for (int r = 0; r < 4; ++r) acc[blk][ct][r] *= sc[r];
      }

      float ts[4] = {0.f, 0.f, 0.f, 0.f};
#pragma unroll
      for (int jb = 0; jb < 4; ++jb)
#pragma unroll
        for (int r = 0; r < 4; ++r) {
          float p = __expf(s[jb][r] - mr[blk][r]);
          ts[r] += p;
          int irow = blk * 16 + 4 * g + r;
          sP[irow * 64 + ((16 * jb + xl) ^ ((irow & 7) << 3))] = f2bf(p);
        }
#pragma unroll
      for (int msk = 1; msk < 16; msk <<= 1)
#pragma unroll
        for (int r = 0; r < 4; ++r) ts[r] += __shfl_xor(ts[r], msk);
#pragma unroll
      for (int r = 0; r < 4; ++r) lr[blk][r] += ts[r];
    }

    // PV: out[i][c] += P[i][j] V[j][c]
#pragma unroll
    for (int jt = 0; jt < 2; ++jt) {
      bf16x8 pf[2];
#pragma unroll
      for (int blk = 0; blk < 2; ++blk) {
        int irow = blk * 16 + xl;
        pf[blk] = *(const bf16x8*)(sP + irow * 64 +
                                   ((jt * 32 + 8 * g) ^ ((irow & 7) << 3)));
      }
#pragma unroll
      for (int ct = 0; ct < 16; ++ct) {
        bf16x8 vf = *(const bf16x8*)(vb + (size_t)(ct * 16 + xl) * NN +
                                     j0 + jt * 32 + 8 * g);
        acc[0][ct] = __builtin_amdgcn_mfma_f32_16x16x32_bf16(pf[0], vf, acc[0][ct], 0, 0, 0);
        acc[1][ct] = __builtin_amdgcn_mfma_f32_16x16x32_bf16(pf[1], vf, acc[1][ct], 0, 0, 0);
      }
    }
  }

  // ---- epilogue: out = gamma * acc/l + x ----
  float linv[2][4];
#pragma unroll
  for (int blk = 0; blk < 2; ++blk)
#pragma unroll
    for (int r = 0; r < 4; ++r) linv[blk][r] = 1.f / lr[blk][r];

#pragma unroll
  for (int blk = 0; blk < 2; ++blk)
#pragma unroll
    for (int ct = 0; ct < 16; ++ct)
#pragma unroll
      for (int r = 0; r < 4; ++r)
        sE[(ct * 16 + xl) * 36 + blk * 16 + 4 * g + r] = acc[blk][ct][r] * linv[blk][r];

  const float gm = gamma[0];
  for (int cc = 0; cc < 32; ++cc) {
    int c   = cc * 8 + (l >> 3);
    int nof = (l & 7) * 4;
    size_t off = ((size_t)b * NC + c) * NN + i0 + nof;
    float4 xv = ld4(x + off);
    float4 t  = ld4(sE + c * 36 + nof);
    float4 o4;
    o4.x = fmaf(gm, t.x, xv.x);
    o4.y = fmaf(gm, t.y, xv.y);
    o4.z = fmaf(gm, t.z, xv.z);
    o4.w = fmaf(gm, t.w, xv.w);
    st4(out + off, o4);
  }
}

// ---------------------------------------------------------------------------
extern "C" void kernel_launch(void* const* d_in, const int* in_sizes, int n_in,
                              void* d_out, int out_size, void* d_ws, size_t ws_size,
                              hipStream_t stream) {
  const float* x     = (const float*)d_in[0];
  const float* wq    = (const float*)d_in[1];
  const float* bq    = (const float*)d_in[2];
  const float* gq    = (const float*)d_in[3];
  const float* betaq = (const float*)d_in[4];
  const float* mq    = (const float*)d_in[5];
  const float* vq    = (const float*)d_in[6];
  const float* wk    = (const float*)d_in[7];
  const float* bk    = (const float*)d_in[8];
  const float* gk    = (const float*)d_in[9];
  const float* betak = (const float*)d_in[10];
  const float* mk    = (const float*)d_in[11];
  const float* vk    = (const float*)d_in[12];
  const float* wv    = (const float*)d_in[13];
  const float* bv    = (const float*)d_in[14];
  const float* gv    = (const float*)d_in[15];
  const float* betav = (const float*)d_in[16];
  const float* mv    = (const float*)d_in[17];
  const float* vv    = (const float*)d_in[18];
  const float* gamma = (const float*)d_in[19];
  float* out = (float*)d_out;

  // workspace: q_bf 2MB | k_bf 2MB | v_bf 16MB (bf16)
  u16* q_bf = (u16*)d_ws;
  u16* k_bf = q_bf + (size_t)NB * NN * 32;
  u16* v_bf = k_bf + (size_t)NB * NN * 32;

  qkv_fused<<<dim3(1280), dim3(256), 0, stream>>>(
      x, wq, bq, gq, betaq, mq, vq,
      wk, bk, gk, betak, mk, vk,
      wv, bv, gv, betav, mv, vv,
      q_bf, k_bf, v_bf);

  attn_mfma<<<dim3(1024), dim3(64), 0, stream>>>(q_bf, k_bf, v_bf, x, gamma, out);
}

// Round 4
// 549.413 us; speedup vs baseline: 3.1129x; 1.1115x over previous
//
#include <hip/hip_runtime.h>
#include <math.h>
#include <stdint.h>
#include <stddef.h>

#define NB 8
#define NC 256
#define NN 4096
#define BN_EPS 1e-5f

typedef unsigned short u16;
typedef __attribute__((ext_vector_type(4))) unsigned short u16x4;
typedef __attribute__((ext_vector_type(8))) short bf16x8;   // 8 bf16 = 4 VGPR
typedef __attribute__((ext_vector_type(4))) float f32x4;

static __device__ __forceinline__ float4 ld4(const float* p) { return *(const float4*)p; }
static __device__ __forceinline__ void st4(float* p, float4 v) { *(float4*)p = v; }
static __device__ __forceinline__ u16 f2bf(float f) {
  uint32_t u = __float_as_uint(f);
  return (u16)((u + 0x7FFFu + ((u >> 16) & 1u)) >> 16);   // RNE
}

// ---------------------------------------------------------------------------
// Kernel 1: fused QKV 1x1-conv + BN + ReLU. fp32 GEMM, bf16 outputs.
//   R4: K-chunks of 32 channels -> LDS 35KB -> 4 WGs/CU (was 52KB/3).
//   q_bf,k_bf : [B][N][32] bf16 ; v_bf : [B][C][N] bf16
// ---------------------------------------------------------------------------
__global__ __launch_bounds__(256) void qkv_fused(
    const float* __restrict__ x,
    const float* __restrict__ wq, const float* __restrict__ bq,
    const float* __restrict__ gq, const float* __restrict__ betaq,
    const float* __restrict__ mq, const float* __restrict__ vq,
    const float* __restrict__ wk, const float* __restrict__ bk,
    const float* __restrict__ gk, const float* __restrict__ betak,
    const float* __restrict__ mk, const float* __restrict__ vk,
    const float* __restrict__ wv, const float* __restrict__ bv,
    const float* __restrict__ gv, const float* __restrict__ betav,
    const float* __restrict__ mv, const float* __restrict__ vv,
    u16* __restrict__ q_bf, u16* __restrict__ k_bf, u16* __restrict__ v_bf)
{
  __shared__ __align__(16) float smem[8704];
  float* sX = smem;          // [32 c][128 n]
  float* sW = smem + 4096;   // [64 o][36]
  float* sT = smem;          // epilogue [128 n][68]

  const int tid   = threadIdx.x;
  const int bx    = blockIdx.x;
  const int b     = bx & 7;
  const int rem   = bx >> 3;
  const int ntile = rem & 31;
  const int otile = rem >> 5;
  const int n0    = ntile * 128;
  const int o0    = otile * 64;

  const int to = tid >> 4;
  const int tn = tid & 15;

  float acc[4][2][4];
#pragma unroll
  for (int j = 0; j < 4; ++j)
#pragma unroll
    for (int r = 0; r < 2; ++r)
#pragma unroll
      for (int e = 0; e < 4; ++e) acc[j][r][e] = 0.f;

  const float* xb = x + (size_t)b * NC * NN + n0;

  for (int ch = 0; ch < 8; ++ch) {
    const int c0 = ch * 32;
#pragma unroll
    for (int p = 0; p < 4; ++p) {          // sX: 1024 float4
      int f = p * 256 + tid;
      int row = f >> 5, col4 = f & 31;
      st4(sX + row * 128 + col4 * 4, ld4(xb + (size_t)(c0 + row) * NN + col4 * 4));
    }
#pragma unroll
    for (int p = 0; p < 2; ++p) {          // sW: 512 float4
      int f = p * 256 + tid;
      int row = f >> 3, col4 = f & 7;
      int o = o0 + row;
      const float* wrow;
      if (o < 32)      wrow = wq + o * NC;
      else if (o < 64) wrow = wk + (o - 32) * NC;
      else             wrow = wv + (o - 64) * NC;
      st4(sW + row * 36 + col4 * 4, ld4(wrow + c0 + col4 * 4));
    }
    __syncthreads();

    for (int cc = 0; cc < 8; ++cc) {
      float wr[4][4];
#pragma unroll
      for (int j = 0; j < 4; ++j) {
        float4 t = ld4(sW + (to * 4 + j) * 36 + cc * 4);
        wr[j][0] = t.x; wr[j][1] = t.y; wr[j][2] = t.z; wr[j][3] = t.w;
      }
      float xr[4][2][4];
#pragma unroll
      for (int lc = 0; lc < 4; ++lc)
#pragma unroll
        for (int r = 0; r < 2; ++r) {
          float4 t = ld4(sX + (cc * 4 + lc) * 128 + tn * 4 + r * 64);
          xr[lc][r][0] = t.x; xr[lc][r][1] = t.y; xr[lc][r][2] = t.z; xr[lc][r][3] = t.w;
        }
#pragma unroll
      for (int j = 0; j < 4; ++j)
#pragma unroll
        for (int lc = 0; lc < 4; ++lc)
#pragma unroll
          for (int r = 0; r < 2; ++r)
#pragma unroll
            for (int e = 0; e < 4; ++e)
              acc[j][r][e] = fmaf(wr[j][lc], xr[lc][r][e], acc[j][r][e]);
    }
    __syncthreads();
  }

  if (otile == 0) {
#pragma unroll
    for (int j = 0; j < 4; ++j) {
      int o = to * 4 + j;
      float bias, g, beta, mean, var;
      if (o < 32) { int d = o;      bias = bq[d]; g = gq[d]; beta = betaq[d]; mean = mq[d]; var = vq[d]; }
      else        { int d = o - 32; bias = bk[d]; g = gk[d]; beta = betak[d]; mean = mk[d]; var = vk[d]; }
      float alpha = g * rsqrtf(var + BN_EPS);
      float delta = (bias - mean) * alpha + beta;
#pragma unroll
      for (int r = 0; r < 2; ++r)
#pragma unroll
        for (int e = 0; e < 4; ++e) {
          float y = fmaxf(fmaf(acc[j][r][e], alpha, delta), 0.f);
          int n = tn * 4 + r * 64 + e;
          sT[n * 68 + to * 4 + j] = y;
        }
    }
    __syncthreads();
    const size_t nrow = (size_t)b * NN + n0;
#pragma unroll
    for (int p = 0; p < 8; ++p) {
      int f = p * 256 + tid;
      int n = f >> 4, col4 = f & 15;
      float4 t = ld4(sT + n * 68 + col4 * 4);
      u16x4 h = { f2bf(t.x), f2bf(t.y), f2bf(t.z), f2bf(t.w) };
      if (col4 < 8) *(u16x4*)(q_bf + (nrow + n) * 32 + col4 * 4) = h;
      else          *(u16x4*)(k_bf + (nrow + n) * 32 + (col4 - 8) * 4) = h;
    }
  } else {
#pragma unroll
    for (int j = 0; j < 4; ++j) {
      int c = (otile - 1) * 64 + to * 4 + j;
      float alpha = gv[c] * rsqrtf(vv[c] + BN_EPS);
      float delta = (bv[c] - mv[c]) * alpha + betav[c];
#pragma unroll
      for (int r = 0; r < 2; ++r) {
        u16x4 h;
#pragma unroll
        for (int e = 0; e < 4; ++e)
          h[e] = f2bf(fmaxf(fmaf(acc[j][r][e], alpha, delta), 0.f));
        int n = n0 + tn * 4 + r * 64;
        *(u16x4*)(v_bf + ((size_t)b * NC + c) * NN + n) = h;
      }
    }
  }
}

// ---------------------------------------------------------------------------
// Kernel 2: MFMA flash attention. R4 restructure for occupancy:
//   WG = 4 waves, 32 q-rows. Each wave: full S + softmax (redundant, no
//   barriers), private swizzled sP (4KB), PV for its own 64 channels
//   (acc 2x4 f32x4 = 32 VGPR). Epilogue: direct float4 RMW of out (lane
//   holds 4 consecutive i for fixed c) -- no LDS transpose buffer.
//   LDS 16KB/WG, target VGPR<=128 -> 4 WGs/CU = 16 waves/CU.
// ---------------------------------------------------------------------------
__global__ __launch_bounds__(256, 4) void attn_mfma(
    const u16* __restrict__ q_bf, const u16* __restrict__ k_bf,
    const u16* __restrict__ v_bf, const float* __restrict__ x,
    const float* __restrict__ gamma, float* __restrict__ out)
{
  __shared__ u16 sP[4 * 32 * 64];             // per-wave swizzled P tiles

  const int tid = threadIdx.x;
  const int w   = tid >> 6;
  const int l   = tid & 63;
  const int xl  = l & 15;
  const int g   = l >> 4;
  const int b   = blockIdx.x & 7;
  const int rt  = blockIdx.x >> 3;            // 0..127
  const int i0  = rt * 32;

  u16* sPw = sP + w * 2048;

  const u16* qb = q_bf + ((size_t)b * NN + i0) * 32;
  const u16* kb = k_bf + (size_t)b * NN * 32;
  const u16* vb = v_bf + (size_t)b * NC * NN + (size_t)(w * 64) * NN;

  // Q A-frags: lane holds Q[i = blk*16+xl][k = 8g..8g+7]
  bf16x8 qf[2];
#pragma unroll
  for (int blk = 0; blk < 2; ++blk)
    qf[blk] = *(const bf16x8*)(qb + (size_t)(blk * 16 + xl) * 32 + 8 * g);

  f32x4 acc[2][4];
#pragma unroll
  for (int blk = 0; blk < 2; ++blk)
#pragma unroll
    for (int ct = 0; ct < 4; ++ct)
      acc[blk][ct] = (f32x4){0.f, 0.f, 0.f, 0.f};

  float mr[2][4], lr[2][4];
#pragma unroll
  for (int blk = 0; blk < 2; ++blk)
#pragma unroll
    for (int r = 0; r < 4; ++r) { mr[blk][r] = -INFINITY; lr[blk][r] = 0.f; }

  for (int jt64 = 0; jt64 < 64; ++jt64) {
    const int j0 = jt64 * 64;

    // K B-frags: lane holds K^T[k=8g..8g+7][j = 16jb+xl]
    bf16x8 kf[4];
#pragma unroll
    for (int jb = 0; jb < 4; ++jb)
      kf[jb] = *(const bf16x8*)(kb + (size_t)(j0 + 16 * jb + xl) * 32 + 8 * g);

#pragma unroll
    for (int blk = 0; blk < 2; ++blk) {
      f32x4 s[4];
#pragma unroll
      for (int jb = 0; jb < 4; ++jb)
        s[jb] = __builtin_amdgcn_mfma_f32_16x16x32_bf16(
            qf[blk], kf[jb], (f32x4){0.f, 0.f, 0.f, 0.f}, 0, 0, 0);
      // lane holds S[row 4g+r (+16 blk)][col 16jb+xl]
      float pm[4];
#pragma unroll
      for (int r = 0; r < 4; ++r)
        pm[r] = fmaxf(fmaxf(s[0][r], s[1][r]), fmaxf(s[2][r], s[3][r]));
#pragma unroll
      for (int msk = 1; msk < 16; msk <<= 1)
#pragma unroll
        for (int r = 0; r < 4; ++r)
          pm[r] = fmaxf(pm[r], __shfl_xor(pm[r], msk));

      bool need = false;
#pragma unroll
      for (int r = 0; r < 4; ++r) need = need || (pm[r] > mr[blk][r]);
      if (__any(need)) {
        float sc[4];
#pragma unroll
        for (int r = 0; r < 4; ++r) {
          float mn = fmaxf(mr[blk][r], pm[r]);
          sc[r] = __expf(mr[blk][r] - mn);
          mr[blk][r] = mn;
          lr[blk][r] *= sc[r];
        }
#pragma unroll
        for (int ct = 0; ct < 4; ++ct)
#pragma unroll
          for (int r = 0; r < 4; ++r) acc[blk][ct][r] *= sc[r];
      }

      float ts[4] = {0.f, 0.f, 0.f, 0.f};
#pragma unroll
      for (int jb = 0; jb < 4; ++jb)
#pragma unroll
        for (int r = 0; r < 4; ++r) {
          float p = __expf(s[jb][r] - mr[blk][r]);
          ts[r] += p;
          int irow = blk * 16 + 4 * g + r;
          sPw[irow * 64 + ((16 * jb + xl) ^ ((irow & 7) << 3))] = f2bf(p);
        }
#pragma unroll
      for (int msk = 1; msk < 16; msk <<= 1)
#pragma unroll
        for (int r = 0; r < 4; ++r) ts[r] += __shfl_xor(ts[r], msk);
#pragma unroll
      for (int r = 0; r < 4; ++r) lr[blk][r] += ts[r];
    }

    // PV for this wave's 64 channels
#pragma unroll
    for (int jt = 0; jt < 2; ++jt) {
      bf16x8 pf[2];
#pragma unroll
      for (int blk = 0; blk < 2; ++blk) {
        int irow = blk * 16 + xl;
        pf[blk] = *(const bf16x8*)(sPw + irow * 64 +
                                   ((jt * 32 + 8 * g) ^ ((irow & 7) << 3)));
      }
#pragma unroll
      for (int ct = 0; ct < 4; ++ct) {
        bf16x8 vf = *(const bf16x8*)(vb + (size_t)(ct * 16 + xl) * NN +
                                     j0 + jt * 32 + 8 * g);
        acc[0][ct] = __builtin_amdgcn_mfma_f32_16x16x32_bf16(pf[0], vf, acc[0][ct], 0, 0, 0);
        acc[1][ct] = __builtin_amdgcn_mfma_f32_16x16x32_bf16(pf[1], vf, acc[1][ct], 0, 0, 0);
      }
    }
  }

  // ---- epilogue: out = gamma * acc/l + x, direct float4 RMW ----
  float linv[2][4];
#pragma unroll
  for (int blk = 0; blk < 2; ++blk)
#pragma unroll
    for (int r = 0; r < 4; ++r) linv[blk][r] = 1.f / lr[blk][r];

  const float gm = gamma[0];
#pragma unroll
  for (int blk = 0; blk < 2; ++blk)
#pragma unroll
    for (int ct = 0; ct < 4; ++ct) {
      int c = w * 64 + ct * 16 + xl;
      size_t off = ((size_t)b * NC + c) * NN + i0 + blk * 16 + 4 * g;
      float4 xv = ld4(x + off);
      float4 o4;
      o4.x = fmaf(gm, acc[blk][ct][0] * linv[blk][0], xv.x);
      o4.y = fmaf(gm, acc[blk][ct][1] * linv[blk][1], xv.y);
      o4.z = fmaf(gm, acc[blk][ct][2] * linv[blk][2], xv.z);
      o4.w = fmaf(gm, acc[blk][ct][3] * linv[blk][3], xv.w);
      st4(out + off, o4);
    }
}

// ---------------------------------------------------------------------------
extern "C" void kernel_launch(void* const* d_in, const int* in_sizes, int n_in,
                              void* d_out, int out_size, void* d_ws, size_t ws_size,
                              hipStream_t stream) {
  const float* x     = (const float*)d_in[0];
  const float* wq    = (const float*)d_in[1];
  const float* bq    = (const float*)d_in[2];
  const float* gq    = (const float*)d_in[3];
  const float* betaq = (const float*)d_in[4];
  const float* mq    = (const float*)d_in[5];
  const float* vq    = (const float*)d_in[6];
  const float* wk    = (const float*)d_in[7];
  const float* bk    = (const float*)d_in[8];
  const float* gk    = (const float*)d_in[9];
  const float* betak = (const float*)d_in[10];
  const float* mk    = (const float*)d_in[11];
  const float* vk    = (const float*)d_in[12];
  const float* wv    = (const float*)d_in[13];
  const float* bv    = (const float*)d_in[14];
  const float* gv    = (const float*)d_in[15];
  const float* betav = (const float*)d_in[16];
  const float* mv    = (const float*)d_in[17];
  const float* vv    = (const float*)d_in[18];
  const float* gamma = (const float*)d_in[19];
  float* out = (float*)d_out;

  u16* q_bf = (u16*)d_ws;
  u16* k_bf = q_bf + (size_t)NB * NN * 32;
  u16* v_bf = k_bf + (size_t)NB * NN * 32;

  qkv_fused<<<dim3(1280), dim3(256), 0, stream>>>(
      x, wq, bq, gq, betaq, mq, vq,
      wk, bk, gk, betak, mk, vk,
      wv, bv, gv, betav, mv, vv,
      q_bf, k_bf, v_bf);

  attn_mfma<<<dim3(1024), dim3(256), 0, stream>>>(q_bf, k_bf, v_bf, x, gamma, out);
}